// Round 8
// baseline (205.326 us; speedup 1.0000x reference)
//
#include <hip/hip_runtime.h>

// CompanionSSM: 256 blocks (1 head), 1024 thr = 16 waves, Blelloch scan.
//  pass1: wave w: 4 chunks (float4+qtr loads, UB in regs), R0..R2 -> own
//         slots, local 4-step scan (f32 C-input) -> Rsum pk -> slot 4w+3.
//  pass2: wave 0: 16 steps with T4 frags (2 MFMA squarings, hi/lo split,
//         r1/r2-verified); entering group states written in place.
//  pass3: wave w: seed from slot 4w+3; per chunk Y = Toep@U + W@S (qtr back,
//         full-line float4 stores); step via stored R (pk) between chunks.
// Serial critical path: 64 steps (r7) -> 16(+4+3). 9 barriers, none in loops.
// LDS 160KB exact: 64 slots 128KB (alias prep G + SQ scratch + phi/kv) +
// FV/FW/FK/FT4 frags 32KB.

#define NKH 256
#define KD  64
#define SL  4096
#define DM  1024

typedef __attribute__((ext_vector_type(8))) short short8;
typedef __attribute__((ext_vector_type(4))) float floatx4;

#define SLOTS_OFF 0
#define SCRA_OFF  0          // f32 64x64  [0,16384)      (slots 0..7)
#define SCRB_OFF  16384      // f32 64x64  [16384,32768)  (= prep G region)
#define PHI_OFF   32768      // f32[128]
#define KV_OFF    33280      // f32[64]
#define FV_OFF    131072
#define FW_OFF    139264
#define FK_OFF    147456
#define FT4_OFF   155648
#define LDS_TOTAL 163840

static __device__ __forceinline__ unsigned pack_bf16(float a, float b) {
  union { float f; unsigned u; } ua, ub;
  ua.f = a; ub.f = b;
  return __builtin_amdgcn_perm(ub.u + 0x8000u, ua.u + 0x8000u, 0x07060302u);
}
static __device__ __forceinline__ unsigned short f2bfru(float x) {
  union { float f; unsigned u; } v; v.f = x;
  return (unsigned short)((v.u + 0x8000u) >> 16);
}
static __device__ __forceinline__ float bflo(unsigned d) {
  union { unsigned u; float f; } v; v.u = d << 16; return v.f;
}
static __device__ __forceinline__ float bfhi(unsigned d) {
  union { unsigned u; float f; } v; v.u = d & 0xffff0000u; return v.f;
}
static __device__ __forceinline__ float bf2f(unsigned short s) {
  union { unsigned u; float f; } v; v.u = ((unsigned)s) << 16; return v.f;
}
static __device__ __forceinline__ float wredsum(float x) {
#pragma unroll
  for (int off = 32; off; off >>= 1) x += __shfl_xor(x, off, 64);
  return x;
}
// 4x4 transpose across a DPP quad (lanes 4k..4k+3, c = lane&3).
static __device__ __forceinline__ float4 qtr(float4 v, int c) {
  const bool c1 = (c & 1) != 0, c2 = (c & 2) != 0;
  float a01 = __shfl_xor(v.y, 1, 64), a10 = __shfl_xor(v.x, 1, 64);
  float a23 = __shfl_xor(v.w, 1, 64), a32 = __shfl_xor(v.z, 1, 64);
  float t0 = c1 ? a01 : v.x, t1 = c1 ? v.y : a10;
  float t2 = c1 ? a23 : v.z, t3 = c1 ? v.w : a32;
  float b02 = __shfl_xor(t2, 2, 64), b20 = __shfl_xor(t0, 2, 64);
  float b13 = __shfl_xor(t3, 2, 64), b31 = __shfl_xor(t1, 2, 64);
  float4 r;
  r.x = c2 ? b02 : t0; r.y = c2 ? b13 : t1;
  r.z = c2 ? t2 : b20; r.w = c2 ? t3 : b31;
  return r;
}
// frag-major 16B-group byte offset for 64x64 bf16
static __device__ __forceinline__ int fmoff(int row, int colg) {
  return ((((row >> 4) * 2 + (colg >> 5)) * 64 + ((colg >> 3) & 3) * 16 + (row & 15)) << 4);
}

// pk (C-layout packed) -> B-frag conversion via 16 shfl (r0-r7 verified)
#define CONV_PK(PK) do { \
  union { short8 v; unsigned uu[4]; } nb0_, nb1_; \
  unsigned xa_, xb_; \
  xa_ = __shfl(PK[0][0], srcA, 64); xb_ = __shfl(PK[1][0], srcA, 64); nb0_.uu[0] = hi ? xb_ : xa_; \
  xa_ = __shfl(PK[0][1], srcA, 64); xb_ = __shfl(PK[1][1], srcA, 64); nb0_.uu[1] = hi ? xb_ : xa_; \
  xa_ = __shfl(PK[0][0], srcB, 64); xb_ = __shfl(PK[1][0], srcB, 64); nb0_.uu[2] = hi ? xb_ : xa_; \
  xa_ = __shfl(PK[0][1], srcB, 64); xb_ = __shfl(PK[1][1], srcB, 64); nb0_.uu[3] = hi ? xb_ : xa_; \
  xa_ = __shfl(PK[2][0], srcA, 64); xb_ = __shfl(PK[3][0], srcA, 64); nb1_.uu[0] = hi ? xb_ : xa_; \
  xa_ = __shfl(PK[2][1], srcA, 64); xb_ = __shfl(PK[3][1], srcA, 64); nb1_.uu[1] = hi ? xb_ : xa_; \
  xa_ = __shfl(PK[2][0], srcB, 64); xb_ = __shfl(PK[3][0], srcB, 64); nb1_.uu[2] = hi ? xb_ : xa_; \
  xa_ = __shfl(PK[2][1], srcB, 64); xb_ = __shfl(PK[3][1], srcB, 64); nb1_.uu[3] = hi ? xb_ : xa_; \
  B0 = nb0_.v; B1 = nb1_.v; \
} while (0)

// one squaring level: DST = SRC @ SRC (64x64 f32, stride 64), hi/lo bf16
// split; one 16x16 tile per wave (16 waves = 16 tiles). r1/r2-verified math.
#define SQ_LEVEL(SRC, DST) do { \
  const int rt_ = w >> 2, ct_ = w & 3; \
  short8 Ah_[2], Al_[2], Bh_[2], Bl_[2]; \
  _Pragma("unroll") \
  for (int kt_ = 0; kt_ < 2; ++kt_) { \
    const float* ap_ = (SRC) + (16*rt_ + n16)*64 + 32*kt_ + 8*quad; \
    union { short8 v; unsigned short us[8]; } ah_, al_, bh_, bl_; \
    _Pragma("unroll") \
    for (int j_ = 0; j_ < 8; ++j_) { \
      float x_ = ap_[j_]; \
      unsigned short hu_ = f2bfru(x_); \
      ah_.us[j_] = (short)hu_; al_.us[j_] = (short)f2bfru(x_ - bf2f(hu_)); \
    } \
    _Pragma("unroll") \
    for (int j_ = 0; j_ < 8; ++j_) { \
      float x_ = (SRC)[(32*kt_ + 8*quad + j_)*64 + 16*ct_ + n16]; \
      unsigned short hu_ = f2bfru(x_); \
      bh_.us[j_] = (short)hu_; bl_.us[j_] = (short)f2bfru(x_ - bf2f(hu_)); \
    } \
    Ah_[kt_] = ah_.v; Al_[kt_] = al_.v; Bh_[kt_] = bh_.v; Bl_[kt_] = bl_.v; \
  } \
  floatx4 d_ = {0.f, 0.f, 0.f, 0.f}; \
  _Pragma("unroll") \
  for (int kt_ = 0; kt_ < 2; ++kt_) { \
    d_ = __builtin_amdgcn_mfma_f32_16x16x32_bf16(Ah_[kt_], Bh_[kt_], d_, 0,0,0); \
    d_ = __builtin_amdgcn_mfma_f32_16x16x32_bf16(Ah_[kt_], Bl_[kt_], d_, 0,0,0); \
    d_ = __builtin_amdgcn_mfma_f32_16x16x32_bf16(Al_[kt_], Bh_[kt_], d_, 0,0,0); \
  } \
  _Pragma("unroll") \
  for (int r_ = 0; r_ < 4; ++r_) \
    (DST)[(16*rt_ + 4*quad + r_)*64 + 16*ct_ + n16] = d_[r_]; \
} while (0)

// load chunk at row base ROW0: 4 float4/lane, full-line (r7 verified)
#define LOADC(ROW0, L) do { \
  L[0] = *(const float4*)(upb + (size_t)((ROW0) + q8 +     rr) * DM); \
  L[1] = *(const float4*)(upb + (size_t)((ROW0) + q8 + 4 + rr) * DM); \
  L[2] = *(const float4*)(upb + (size_t)((ROW0) + 32 + q8 +     rr) * DM); \
  L[3] = *(const float4*)(upb + (size_t)((ROW0) + 32 + q8 + 4 + rr) * DM); \
} while (0)

// pass1 chunk J: transpose -> UB[J], R = V@U; if J<3 write R pk to slot J,
// local step B <- T@B + R (f32 C-input); J==3: write step pk (Rsum) to slot 3.
#define PRODCHUNK(J, L) do { \
  const float4 W00_ = qtr(L[0], rr), W01_ = qtr(L[1], rr); \
  const float4 W10_ = qtr(L[2], rr), W11_ = qtr(L[3], rr); \
  union { short8 v; unsigned s4[4]; } u0_, u1_; \
  u0_.s4[0] = pack_bf16(W00_.x, W00_.y); u0_.s4[1] = pack_bf16(W00_.z, W00_.w); \
  u0_.s4[2] = pack_bf16(W01_.x, W01_.y); u0_.s4[3] = pack_bf16(W01_.z, W01_.w); \
  u1_.s4[0] = pack_bf16(W10_.x, W10_.y); u1_.s4[1] = pack_bf16(W10_.z, W10_.w); \
  u1_.s4[2] = pack_bf16(W11_.x, W11_.y); u1_.s4[3] = pack_bf16(W11_.z, W11_.w); \
  UB[J][0] = u0_.v; UB[J][1] = u1_.v; \
  floatx4 racc_[4]; \
  _Pragma("unroll") \
  for (int rt_ = 0; rt_ < 4; ++rt_) { \
    const short8 v0_ = *(const short8*)(lds + FV_OFF + (((rt_*2 + 0)*64 + lane) << 4)); \
    const short8 v1_ = *(const short8*)(lds + FV_OFF + (((rt_*2 + 1)*64 + lane) << 4)); \
    floatx4 r_ = {0.f, 0.f, 0.f, 0.f}; \
    r_ = __builtin_amdgcn_mfma_f32_16x16x32_bf16(v0_, u0_.v, r_, 0,0,0); \
    racc_[rt_] = __builtin_amdgcn_mfma_f32_16x16x32_bf16(v1_, u1_.v, r_, 0,0,0); \
  } \
  if ((J) < 3) { \
    _Pragma("unroll") \
    for (int rt_ = 0; rt_ < 4; ++rt_) { \
      uint2 pr_; pr_.x = pack_bf16(racc_[rt_][0], racc_[rt_][1]); \
      pr_.y = pack_bf16(racc_[rt_][2], racc_[rt_][3]); \
      *(uint2*)(myslot + (J)*2048 + rt_*512 + lane*8) = pr_; \
    } \
  } \
  unsigned pk_[4][2]; \
  _Pragma("unroll") \
  for (int rt_ = 0; rt_ < 4; ++rt_) { \
    floatx4 a0_ = __builtin_amdgcn_mfma_f32_16x16x32_bf16(At[rt_][0], B0, racc_[rt_], 0,0,0); \
    floatx4 ac_ = __builtin_amdgcn_mfma_f32_16x16x32_bf16(At[rt_][1], B1, a0_, 0,0,0); \
    pk_[rt_][0] = pack_bf16(ac_[0], ac_[1]); \
    pk_[rt_][1] = pack_bf16(ac_[2], ac_[3]); \
  } \
  if ((J) < 3) { CONV_PK(pk_); } \
  else { \
    _Pragma("unroll") \
    for (int rt_ = 0; rt_ < 4; ++rt_) { \
      uint2 pq_; pq_.x = pk_[rt_][0]; pq_.y = pk_[rt_][1]; \
      *(uint2*)(myslot + 3*2048 + rt_*512 + lane*8) = pq_; \
    } \
  } \
} while (0)

// pass3 chunk J: Y = Toep@U + W@B (store); if J<3 step B via slot-J R pk.
#define CONSCHUNK(J) do { \
  _Pragma("unroll") \
  for (int rt_ = 0; rt_ < 4; ++rt_) { \
    const short8 k0_ = *(const short8*)(lds + FK_OFF + (((rt_*2 + 0)*64 + lane) << 4)); \
    const short8 k1_ = *(const short8*)(lds + FK_OFF + (((rt_*2 + 1)*64 + lane) << 4)); \
    const short8 w0_ = *(const short8*)(lds + FW_OFF + (((rt_*2 + 0)*64 + lane) << 4)); \
    const short8 w1_ = *(const short8*)(lds + FW_OFF + (((rt_*2 + 1)*64 + lane) << 4)); \
    floatx4 ty_ = {0.f, 0.f, 0.f, 0.f}; \
    ty_ = __builtin_amdgcn_mfma_f32_16x16x32_bf16(k0_, UB[J][0], ty_, 0,0,0); \
    ty_ = __builtin_amdgcn_mfma_f32_16x16x32_bf16(k1_, UB[J][1], ty_, 0,0,0); \
    ty_ = __builtin_amdgcn_mfma_f32_16x16x32_bf16(w0_, B0, ty_, 0,0,0); \
    ty_ = __builtin_amdgcn_mfma_f32_16x16x32_bf16(w1_, B1, ty_, 0,0,0); \
    float4 yv_; yv_.x = ty_[0]; yv_.y = ty_[1]; yv_.z = ty_[2]; yv_.w = ty_[3]; \
    const float4 tw_ = qtr(yv_, rr); \
    *(float4*)(opb + (size_t)((c0 + (J))*64 + 16*rt_ + 4*quad + rr) * DM) = tw_; \
  } \
  if ((J) < 3) { \
    uint2 rb_[4]; \
    _Pragma("unroll") \
    for (int rt_ = 0; rt_ < 4; ++rt_) \
      rb_[rt_] = *(const uint2*)(myslot + (J)*2048 + rt_*512 + lane*8); \
    unsigned pk_[4][2]; \
    _Pragma("unroll") \
    for (int rt_ = 0; rt_ < 4; ++rt_) { \
      floatx4 cs_; \
      cs_[0] = bflo(rb_[rt_].x); cs_[1] = bfhi(rb_[rt_].x); \
      cs_[2] = bflo(rb_[rt_].y); cs_[3] = bfhi(rb_[rt_].y); \
      floatx4 a0_ = __builtin_amdgcn_mfma_f32_16x16x32_bf16(At[rt_][0], B0, cs_, 0,0,0); \
      floatx4 ac_ = __builtin_amdgcn_mfma_f32_16x16x32_bf16(At[rt_][1], B1, a0_, 0,0,0); \
      pk_[rt_][0] = pack_bf16(ac_[0], ac_[1]); \
      pk_[rt_][1] = pack_bf16(ac_[2], ac_[3]); \
    } \
    CONV_PK(pk_); \
  } \
} while (0)

__global__ __launch_bounds__(1024, 4) void fused_kernel(
    const float* __restrict__ u, const float* __restrict__ ga,
    const float* __restrict__ gb, const float* __restrict__ gc,
    float* __restrict__ out)
{
  __shared__ __align__(16) char lds[LDS_TOTAL];
  unsigned short* G = (unsigned short*)lds;     // prep: rows 64..127, stride 128
  float* phi  = (float*)(lds + PHI_OFF);
  float* kv   = (float*)(lds + KV_OFF);
  float* scrA = (float*)(lds + SCRA_OFF);
  float* scrB = (float*)(lds + SCRB_OFF);

  const int i = blockIdx.x;
  const int h = 8 * (i & 31) + (i >> 5);        // co-line heads -> same XCD
  const int t = threadIdx.x;
  const int w = t >> 6, lane = t & 63;
  const int n16 = lane & 15, quad = lane >> 4;
  const int rr = lane & 3, q8 = quad * 8, bqi = (lane >> 2) & 3;

  // ---------------- prep chains (waves 0,1; no in-loop reductions) --------
  if (w < 2) {
    const float av = ga[h*KD + lane];
    const float an = av / wredsum(fabsf(av));   // mean(|rowsum|) >> eps
    if (w == 1) {
      phi[lane] = gc[h*KD + lane];              // phi[0..63] = c
      float g = an;                             // g_64 = A^64 e0 = a_n
      for (int p = 64; p < 128; ++p) {
        G[(64 + lane)*128 + (p - 64)] = f2bfru(g);   // T col m = g_{64+m}
        const float top = __shfl(g, 63, 64);
        const float gm1 = __shfl_up(g, 1, 64);
        g = (lane > 0 ? gm1 : 0.0f) + an * top;
      }
    } else {
      float v = gb[h*KD + lane];                // v_j = A^j b
      for (int j = 0; j < KD; ++j) {
        G[(64 + lane)*128 + 64 + (63 - j)] = f2bfru(v);  // V col m = v_{63-m}
        const float top = __shfl(v, 63, 64);
        const float vm1 = __shfl_up(v, 1, 64);
        v = (lane > 0 ? vm1 : 0.0f) + an * top;
      }
    }
  }
  __syncthreads();

  // ------- deferred dot products: phi[64..127] and kv[0..63] -------
  if (t < 128) {
    float acc = 0.f;
    for (int n = 0; n < 64; ++n)
      acc += phi[n] * bf2f(G[(64 + n)*128 + t]);
    if (t < 64) phi[64 + t] = acc;      // phi[p] = c . g_p
    else        kv[127 - t] = acc;      // kv[j] = c . v_j
  }
  __syncthreads();

  // ---- fills: FV copy, FW/FK direct, At (all waves), T -> scrA (f32) ----
  if (t < 512) {
    const int f = t >> 6, l = t & 63;           // V frags
    const int rt = f >> 1, kt = f & 1;
    const int ln = l & 15, lq2 = l >> 4;
    *(uint4*)(lds + FV_OFF + ((f*64 + l) << 4)) =
        *(const uint4*)(G + (64 + 16*rt + ln)*128 + 64 + 32*kt + 8*lq2);
  }
  if (t < 512) {
    const int cgi = t >> 6, row = t & 63;       // W/K frags
    const int colg = cgi * 8;
    union { short8 v; unsigned short us[8]; } wb, kb;
#pragma unroll
    for (int jj = 0; jj < 8; ++jj) {
      wb.us[jj] = f2bfru(phi[row + 1 + colg + jj]);
      const int mm = colg + jj;
      kb.us[jj] = (mm <= row) ? f2bfru(kv[row - mm]) : (unsigned short)0;
    }
    *(short8*)(lds + FW_OFF + fmoff(row, colg)) = wb.v;
    *(short8*)(lds + FK_OFF + fmoff(row, colg)) = kb.v;
  }
  short8 At[4][2];
#pragma unroll
  for (int rt = 0; rt < 4; ++rt)
#pragma unroll
    for (int kt = 0; kt < 2; ++kt)
      At[rt][kt] = *(const short8*)(G + (64 + 16*rt + n16)*128 + 32*kt + quad*8);
  for (int idx = t; idx < 4096; idx += 1024) {  // T -> scrA f32 (disjoint of G)
    const int row = idx >> 6, col = idx & 63;
    scrA[row*64 + col] = bf2f(G[(64 + row)*128 + col]);
  }
  __syncthreads();

  // ---------------- T4 = (T^2)^2 via 2 squarings ----------------
  SQ_LEVEL(scrA, scrB);   // T2 (scrB aliases dead G region)
  __syncthreads();
  SQ_LEVEL(scrB, scrA);   // T4
  __syncthreads();
  if (w < 8) {            // At4 frags -> FT4
    const int rt4 = w >> 1, kt4 = w & 1;
    union { short8 v; unsigned short us[8]; } a4;
#pragma unroll
    for (int j = 0; j < 8; ++j)
      a4.us[j] = (short)f2bfru(scrA[(16*rt4 + n16)*64 + 32*kt4 + 8*quad + j]);
    *(short8*)(lds + FT4_OFF + (((rt4*2 + kt4)*64 + lane) << 4)) = a4.v;
  }
  __syncthreads();        // scratch + G dead -> slots usable

  // ---------------- pass1: 4 chunks/wave, local scan ----------------
  const float* upb = u   + (size_t)bqi * ((size_t)SL * DM) + 4*h;
  float*       opb = out + (size_t)bqi * ((size_t)SL * DM) + 4*h;
  const int c0 = 4 * w;                   // wave's first global chunk
  char* myslot = lds + SLOTS_OFF + c0 * 2048;
  const int srcA = n16 + 16*((2*quad) & 3);
  const int srcB = n16 + 16*((2*quad + 1) & 3);
  const bool hi = (quad >= 2);
  const short8 Z8 = {0,0,0,0,0,0,0,0};
  short8 B0 = Z8, B1 = Z8;
  short8 UB[4][2];

  {
    float4 LA[4], LB[4];
    LOADC(c0*64, LA);
    LOADC((c0 + 1)*64, LB);
    PRODCHUNK(0, LA);
    LOADC((c0 + 2)*64, LA);
    PRODCHUNK(1, LB);
    LOADC((c0 + 3)*64, LB);
    PRODCHUNK(2, LA);
    PRODCHUNK(3, LB);
  }
  __syncthreads();

  // ---------------- pass2: wave 0, 16 steps with T4 ----------------
  if (w == 0) {
    short8 At4[4][2];
#pragma unroll
    for (int rt = 0; rt < 4; ++rt)
#pragma unroll
      for (int kt = 0; kt < 2; ++kt)
        At4[rt][kt] = *(const short8*)(lds + FT4_OFF + (((rt*2 + kt)*64 + lane) << 4));
    B0 = Z8; B1 = Z8;
#pragma unroll 1
    for (int g = 0; g < 16; ++g) {
      char* sp = lds + SLOTS_OFF + (4*g + 3) * 2048;
      uint2 rb[4];
#pragma unroll
      for (int rt = 0; rt < 4; ++rt) rb[rt] = *(const uint2*)(sp + rt*512 + lane*8);
      asm volatile("" ::: "memory");
      *(short8*)(sp + lane*16)        = B0;   // entering state of group g
      *(short8*)(sp + 1024 + lane*16) = B1;
      unsigned pk[4][2];
#pragma unroll
      for (int rt = 0; rt < 4; ++rt) {
        floatx4 cs;
        cs[0] = bflo(rb[rt].x); cs[1] = bfhi(rb[rt].x);
        cs[2] = bflo(rb[rt].y); cs[3] = bfhi(rb[rt].y);
        floatx4 a0 = __builtin_amdgcn_mfma_f32_16x16x32_bf16(At4[rt][0], B0, cs, 0,0,0);
        floatx4 ac = __builtin_amdgcn_mfma_f32_16x16x32_bf16(At4[rt][1], B1, a0, 0,0,0);
        pk[rt][0] = pack_bf16(ac[0], ac[1]);
        pk[rt][1] = pack_bf16(ac[2], ac[3]);
      }
      CONV_PK(pk);
    }
  }
  __syncthreads();

  // ---------------- pass3: seed + 4 chunks/wave ----------------
  B0 = *(const short8*)(myslot + 3*2048 + lane*16);
  B1 = *(const short8*)(myslot + 3*2048 + 1024 + lane*16);
  CONSCHUNK(0);
  CONSCHUNK(1);
  CONSCHUNK(2);
  CONSCHUNK(3);
}

// ---------------------------------------------------------------- launch --
extern "C" void kernel_launch(void* const* d_in, const int* in_sizes, int n_in,
                              void* d_out, int out_size, void* d_ws, size_t ws_size,
                              hipStream_t stream)
{
  const float* u = (const float*)d_in[0];
  const float* a = (const float*)d_in[1];
  const float* b = (const float*)d_in[2];
  const float* c = (const float*)d_in[3];
  float* out = (float*)d_out;
  (void)d_ws; (void)ws_size; (void)in_sizes; (void)n_in; (void)out_size;

  fused_kernel<<<NKH, 1024, 0, stream>>>(u, a, b, c, out);
}

// Round 9
// 189.327 us; speedup vs baseline: 1.0845x; 1.0845x over previous
//
#include <hip/hip_runtime.h>

// CompanionSSM: 256 blocks (1 head), 1024 thr = 16 waves, Blelloch scan.
// == Round-8 structure (correctness-proven) with the register diet that
// removes r8's spills (WRITE 124MB -> target 65536KB exact):
//  - no UB[] register array: pass3 re-reads u (L3-resident by then) and
//    rebuilds U frags just-in-time (bit-identical loads/transpose/pack)
//  - single-buffered chunk loads (LOADC inside PRODCHUNK/CONSCHUNK)
//  - At4 only live inside pass2 (loaded from FT4 after pass1 barrier)
// Passes:
//  pass1: wave w, chunks 4w..4w+3: R = V@U -> own slots (pk), local 4-step
//         scan (f32 C-input) -> group Rsum pk -> slot 4w+3.
//  pass2: wave 0: 16 steps with T4 frags (2 hi/lo-split MFMA squarings);
//         entering group states written in place over the Rsums.
//  pass3: wave w: seed from slot 4w+3; per chunk rebuild U, Y = Toep@U + W@S
//         (qtr back, full-line float4 stores); step via stored R pk (J<3).
// LDS 160KB exact: 64 slots 128KB (alias prep G + SQ scratch + phi/kv) +
// FV/FW/FK/FT4 frags 32KB.

#define NKH 256
#define KD  64
#define SL  4096
#define DM  1024

typedef __attribute__((ext_vector_type(8))) short short8;
typedef __attribute__((ext_vector_type(4))) float floatx4;

#define SLOTS_OFF 0
#define SCRA_OFF  0          // f32 64x64  [0,16384)      (slots 0..7)
#define SCRB_OFF  16384      // f32 64x64  [16384,32768)  (= prep G region)
#define PHI_OFF   32768      // f32[128]  (slots 16.. region, prep-only)
#define KV_OFF    33280      // f32[64]
#define FV_OFF    131072
#define FW_OFF    139264
#define FK_OFF    147456
#define FT4_OFF   155648
#define LDS_TOTAL 163840

static __device__ __forceinline__ unsigned pack_bf16(float a, float b) {
  union { float f; unsigned u; } ua, ub;
  ua.f = a; ub.f = b;
  return __builtin_amdgcn_perm(ub.u + 0x8000u, ua.u + 0x8000u, 0x07060302u);
}
static __device__ __forceinline__ unsigned short f2bfru(float x) {
  union { float f; unsigned u; } v; v.f = x;
  return (unsigned short)((v.u + 0x8000u) >> 16);
}
static __device__ __forceinline__ float bflo(unsigned d) {
  union { unsigned u; float f; } v; v.u = d << 16; return v.f;
}
static __device__ __forceinline__ float bfhi(unsigned d) {
  union { unsigned u; float f; } v; v.u = d & 0xffff0000u; return v.f;
}
static __device__ __forceinline__ float bf2f(unsigned short s) {
  union { unsigned u; float f; } v; v.u = ((unsigned)s) << 16; return v.f;
}
static __device__ __forceinline__ float wredsum(float x) {
#pragma unroll
  for (int off = 32; off; off >>= 1) x += __shfl_xor(x, off, 64);
  return x;
}
// 4x4 transpose across a DPP quad (lanes 4k..4k+3, c = lane&3).
static __device__ __forceinline__ float4 qtr(float4 v, int c) {
  const bool c1 = (c & 1) != 0, c2 = (c & 2) != 0;
  float a01 = __shfl_xor(v.y, 1, 64), a10 = __shfl_xor(v.x, 1, 64);
  float a23 = __shfl_xor(v.w, 1, 64), a32 = __shfl_xor(v.z, 1, 64);
  float t0 = c1 ? a01 : v.x, t1 = c1 ? v.y : a10;
  float t2 = c1 ? a23 : v.z, t3 = c1 ? v.w : a32;
  float b02 = __shfl_xor(t2, 2, 64), b20 = __shfl_xor(t0, 2, 64);
  float b13 = __shfl_xor(t3, 2, 64), b31 = __shfl_xor(t1, 2, 64);
  float4 r;
  r.x = c2 ? b02 : t0; r.y = c2 ? b13 : t1;
  r.z = c2 ? t2 : b20; r.w = c2 ? t3 : b31;
  return r;
}
// frag-major 16B-group byte offset for 64x64 bf16
static __device__ __forceinline__ int fmoff(int row, int colg) {
  return ((((row >> 4) * 2 + (colg >> 5)) * 64 + ((colg >> 3) & 3) * 16 + (row & 15)) << 4);
}

// pk (C-layout packed) -> B-frag conversion via 16 shfl (r0-r8 verified)
#define CONV_PK(PK) do { \
  union { short8 v; unsigned uu[4]; } nb0_, nb1_; \
  unsigned xa_, xb_; \
  xa_ = __shfl(PK[0][0], srcA, 64); xb_ = __shfl(PK[1][0], srcA, 64); nb0_.uu[0] = hi ? xb_ : xa_; \
  xa_ = __shfl(PK[0][1], srcA, 64); xb_ = __shfl(PK[1][1], srcA, 64); nb0_.uu[1] = hi ? xb_ : xa_; \
  xa_ = __shfl(PK[0][0], srcB, 64); xb_ = __shfl(PK[1][0], srcB, 64); nb0_.uu[2] = hi ? xb_ : xa_; \
  xa_ = __shfl(PK[0][1], srcB, 64); xb_ = __shfl(PK[1][1], srcB, 64); nb0_.uu[3] = hi ? xb_ : xa_; \
  xa_ = __shfl(PK[2][0], srcA, 64); xb_ = __shfl(PK[3][0], srcA, 64); nb1_.uu[0] = hi ? xb_ : xa_; \
  xa_ = __shfl(PK[2][1], srcA, 64); xb_ = __shfl(PK[3][1], srcA, 64); nb1_.uu[1] = hi ? xb_ : xa_; \
  xa_ = __shfl(PK[2][0], srcB, 64); xb_ = __shfl(PK[3][0], srcB, 64); nb1_.uu[2] = hi ? xb_ : xa_; \
  xa_ = __shfl(PK[2][1], srcB, 64); xb_ = __shfl(PK[3][1], srcB, 64); nb1_.uu[3] = hi ? xb_ : xa_; \
  B0 = nb0_.v; B1 = nb1_.v; \
} while (0)

// one squaring level: DST = SRC @ SRC (64x64 f32, stride 64), hi/lo bf16
// split; one 16x16 tile per wave (16 waves = 16 tiles). r1/r2/r8-verified.
#define SQ_LEVEL(SRC, DST) do { \
  const int rt_ = w >> 2, ct_ = w & 3; \
  short8 Ah_[2], Al_[2], Bh_[2], Bl_[2]; \
  _Pragma("unroll") \
  for (int kt_ = 0; kt_ < 2; ++kt_) { \
    const float* ap_ = (SRC) + (16*rt_ + n16)*64 + 32*kt_ + 8*quad; \
    union { short8 v; unsigned short us[8]; } ah_, al_, bh_, bl_; \
    _Pragma("unroll") \
    for (int j_ = 0; j_ < 8; ++j_) { \
      float x_ = ap_[j_]; \
      unsigned short hu_ = f2bfru(x_); \
      ah_.us[j_] = (short)hu_; al_.us[j_] = (short)f2bfru(x_ - bf2f(hu_)); \
    } \
    _Pragma("unroll") \
    for (int j_ = 0; j_ < 8; ++j_) { \
      float x_ = (SRC)[(32*kt_ + 8*quad + j_)*64 + 16*ct_ + n16]; \
      unsigned short hu_ = f2bfru(x_); \
      bh_.us[j_] = (short)hu_; bl_.us[j_] = (short)f2bfru(x_ - bf2f(hu_)); \
    } \
    Ah_[kt_] = ah_.v; Al_[kt_] = al_.v; Bh_[kt_] = bh_.v; Bl_[kt_] = bl_.v; \
  } \
  floatx4 d_ = {0.f, 0.f, 0.f, 0.f}; \
  _Pragma("unroll") \
  for (int kt_ = 0; kt_ < 2; ++kt_) { \
    d_ = __builtin_amdgcn_mfma_f32_16x16x32_bf16(Ah_[kt_], Bh_[kt_], d_, 0,0,0); \
    d_ = __builtin_amdgcn_mfma_f32_16x16x32_bf16(Ah_[kt_], Bl_[kt_], d_, 0,0,0); \
    d_ = __builtin_amdgcn_mfma_f32_16x16x32_bf16(Al_[kt_], Bh_[kt_], d_, 0,0,0); \
  } \
  _Pragma("unroll") \
  for (int r_ = 0; r_ < 4; ++r_) \
    (DST)[(16*rt_ + 4*quad + r_)*64 + 16*ct_ + n16] = d_[r_]; \
} while (0)

// load chunk at row base ROW0: 4 float4/lane, full-line (r7/r8 verified)
#define LOADC(ROW0, L) do { \
  L[0] = *(const float4*)(upb + (size_t)((ROW0) + q8 +     rr) * DM); \
  L[1] = *(const float4*)(upb + (size_t)((ROW0) + q8 + 4 + rr) * DM); \
  L[2] = *(const float4*)(upb + (size_t)((ROW0) + 32 + q8 +     rr) * DM); \
  L[3] = *(const float4*)(upb + (size_t)((ROW0) + 32 + q8 + 4 + rr) * DM); \
} while (0)

// transpose + pack loaded chunk -> U B-frags U0_,U1_ (locals of enclosing blk)
#define MAKEU(L) \
  const float4 W00_ = qtr(L[0], rr), W01_ = qtr(L[1], rr); \
  const float4 W10_ = qtr(L[2], rr), W11_ = qtr(L[3], rr); \
  union { short8 v; unsigned s4[4]; } U0_, U1_; \
  U0_.s4[0] = pack_bf16(W00_.x, W00_.y); U0_.s4[1] = pack_bf16(W00_.z, W00_.w); \
  U0_.s4[2] = pack_bf16(W01_.x, W01_.y); U0_.s4[3] = pack_bf16(W01_.z, W01_.w); \
  U1_.s4[0] = pack_bf16(W10_.x, W10_.y); U1_.s4[1] = pack_bf16(W10_.z, W10_.w); \
  U1_.s4[2] = pack_bf16(W11_.x, W11_.y); U1_.s4[3] = pack_bf16(W11_.z, W11_.w);

// pass1 chunk J: load, R = V@U; J<3: R pk -> slot J, step B <- T@B + R
// (f32 C-input); J==3: step pk (Rsum) -> slot 3.
#define PRODCHUNK(J) do { \
  float4 L_[4]; \
  LOADC((c0 + (J))*64, L_); \
  MAKEU(L_); \
  floatx4 racc_[4]; \
  _Pragma("unroll") \
  for (int rt_ = 0; rt_ < 4; ++rt_) { \
    const short8 v0_ = *(const short8*)(lds + FV_OFF + (((rt_*2 + 0)*64 + lane) << 4)); \
    const short8 v1_ = *(const short8*)(lds + FV_OFF + (((rt_*2 + 1)*64 + lane) << 4)); \
    floatx4 r_ = {0.f, 0.f, 0.f, 0.f}; \
    r_ = __builtin_amdgcn_mfma_f32_16x16x32_bf16(v0_, U0_.v, r_, 0,0,0); \
    racc_[rt_] = __builtin_amdgcn_mfma_f32_16x16x32_bf16(v1_, U1_.v, r_, 0,0,0); \
  } \
  if ((J) < 3) { \
    _Pragma("unroll") \
    for (int rt_ = 0; rt_ < 4; ++rt_) { \
      uint2 pr_; pr_.x = pack_bf16(racc_[rt_][0], racc_[rt_][1]); \
      pr_.y = pack_bf16(racc_[rt_][2], racc_[rt_][3]); \
      *(uint2*)(myslot + (J)*2048 + rt_*512 + lane*8) = pr_; \
    } \
  } \
  unsigned pk_[4][2]; \
  _Pragma("unroll") \
  for (int rt_ = 0; rt_ < 4; ++rt_) { \
    floatx4 a0_ = __builtin_amdgcn_mfma_f32_16x16x32_bf16(At[rt_][0], B0, racc_[rt_], 0,0,0); \
    floatx4 ac_ = __builtin_amdgcn_mfma_f32_16x16x32_bf16(At[rt_][1], B1, a0_, 0,0,0); \
    pk_[rt_][0] = pack_bf16(ac_[0], ac_[1]); \
    pk_[rt_][1] = pack_bf16(ac_[2], ac_[3]); \
  } \
  if ((J) < 3) { CONV_PK(pk_); } \
  else { \
    _Pragma("unroll") \
    for (int rt_ = 0; rt_ < 4; ++rt_) { \
      uint2 pq_; pq_.x = pk_[rt_][0]; pq_.y = pk_[rt_][1]; \
      *(uint2*)(myslot + 3*2048 + rt_*512 + lane*8) = pq_; \
    } \
  } \
} while (0)

// pass3 chunk J: re-load u (L3-hit), rebuild U; Y = Toep@U + W@B (store);
// J<3: step B via slot-J R pk.
#define CONSCHUNK(J) do { \
  float4 L_[4]; \
  LOADC((c0 + (J))*64, L_); \
  MAKEU(L_); \
  _Pragma("unroll") \
  for (int rt_ = 0; rt_ < 4; ++rt_) { \
    const short8 k0_ = *(const short8*)(lds + FK_OFF + (((rt_*2 + 0)*64 + lane) << 4)); \
    const short8 k1_ = *(const short8*)(lds + FK_OFF + (((rt_*2 + 1)*64 + lane) << 4)); \
    const short8 w0_ = *(const short8*)(lds + FW_OFF + (((rt_*2 + 0)*64 + lane) << 4)); \
    const short8 w1_ = *(const short8*)(lds + FW_OFF + (((rt_*2 + 1)*64 + lane) << 4)); \
    floatx4 ty_ = {0.f, 0.f, 0.f, 0.f}; \
    ty_ = __builtin_amdgcn_mfma_f32_16x16x32_bf16(k0_, U0_.v, ty_, 0,0,0); \
    ty_ = __builtin_amdgcn_mfma_f32_16x16x32_bf16(k1_, U1_.v, ty_, 0,0,0); \
    ty_ = __builtin_amdgcn_mfma_f32_16x16x32_bf16(w0_, B0, ty_, 0,0,0); \
    ty_ = __builtin_amdgcn_mfma_f32_16x16x32_bf16(w1_, B1, ty_, 0,0,0); \
    float4 yv_; yv_.x = ty_[0]; yv_.y = ty_[1]; yv_.z = ty_[2]; yv_.w = ty_[3]; \
    const float4 tw_ = qtr(yv_, rr); \
    *(float4*)(opb + (size_t)((c0 + (J))*64 + 16*rt_ + 4*quad + rr) * DM) = tw_; \
  } \
  if ((J) < 3) { \
    uint2 rb_[4]; \
    _Pragma("unroll") \
    for (int rt_ = 0; rt_ < 4; ++rt_) \
      rb_[rt_] = *(const uint2*)(myslot + (J)*2048 + rt_*512 + lane*8); \
    unsigned pk_[4][2]; \
    _Pragma("unroll") \
    for (int rt_ = 0; rt_ < 4; ++rt_) { \
      floatx4 cs_; \
      cs_[0] = bflo(rb_[rt_].x); cs_[1] = bfhi(rb_[rt_].x); \
      cs_[2] = bflo(rb_[rt_].y); cs_[3] = bfhi(rb_[rt_].y); \
      floatx4 a0_ = __builtin_amdgcn_mfma_f32_16x16x32_bf16(At[rt_][0], B0, cs_, 0,0,0); \
      floatx4 ac_ = __builtin_amdgcn_mfma_f32_16x16x32_bf16(At[rt_][1], B1, a0_, 0,0,0); \
      pk_[rt_][0] = pack_bf16(ac_[0], ac_[1]); \
      pk_[rt_][1] = pack_bf16(ac_[2], ac_[3]); \
    } \
    CONV_PK(pk_); \
  } \
} while (0)

__global__ __launch_bounds__(1024, 4) void fused_kernel(
    const float* __restrict__ u, const float* __restrict__ ga,
    const float* __restrict__ gb, const float* __restrict__ gc,
    float* __restrict__ out)
{
  __shared__ __align__(16) char lds[LDS_TOTAL];
  unsigned short* G = (unsigned short*)lds;     // prep: rows 64..127, stride 128
  float* phi  = (float*)(lds + PHI_OFF);
  float* kv   = (float*)(lds + KV_OFF);
  float* scrA = (float*)(lds + SCRA_OFF);
  float* scrB = (float*)(lds + SCRB_OFF);

  const int i = blockIdx.x;
  const int h = 8 * (i & 31) + (i >> 5);        // co-line heads -> same XCD
  const int t = threadIdx.x;
  const int w = t >> 6, lane = t & 63;
  const int n16 = lane & 15, quad = lane >> 4;
  const int rr = lane & 3, q8 = quad * 8, bqi = (lane >> 2) & 3;

  // ---------------- prep chains (waves 0,1; no in-loop reductions) --------
  if (w < 2) {
    const float av = ga[h*KD + lane];
    const float an = av / wredsum(fabsf(av));   // mean(|rowsum|) >> eps
    if (w == 1) {
      phi[lane] = gc[h*KD + lane];              // phi[0..63] = c
      float g = an;                             // g_64 = A^64 e0 = a_n
      for (int p = 64; p < 128; ++p) {
        G[(64 + lane)*128 + (p - 64)] = f2bfru(g);   // T col m = g_{64+m}
        const float top = __shfl(g, 63, 64);
        const float gm1 = __shfl_up(g, 1, 64);
        g = (lane > 0 ? gm1 : 0.0f) + an * top;
      }
    } else {
      float v = gb[h*KD + lane];                // v_j = A^j b
      for (int j = 0; j < KD; ++j) {
        G[(64 + lane)*128 + 64 + (63 - j)] = f2bfru(v);  // V col m = v_{63-m}
        const float top = __shfl(v, 63, 64);
        const float vm1 = __shfl_up(v, 1, 64);
        v = (lane > 0 ? vm1 : 0.0f) + an * top;
      }
    }
  }
  __syncthreads();

  // ------- deferred dot products: phi[64..127] and kv[0..63] -------
  if (t < 128) {
    float acc = 0.f;
    for (int n = 0; n < 64; ++n)
      acc += phi[n] * bf2f(G[(64 + n)*128 + t]);
    if (t < 64) phi[64 + t] = acc;      // phi[p] = c . g_p
    else        kv[127 - t] = acc;      // kv[j] = c . v_j
  }
  __syncthreads();

  // ---- fills: FV copy, FW/FK direct, At (all waves), T -> scrA (f32) ----
  if (t < 512) {
    const int f = t >> 6, l = t & 63;           // V frags
    const int rt = f >> 1, kt = f & 1;
    const int ln = l & 15, lq2 = l >> 4;
    *(uint4*)(lds + FV_OFF + ((f*64 + l) << 4)) =
        *(const uint4*)(G + (64 + 16*rt + ln)*128 + 64 + 32*kt + 8*lq2);
  }
  if (t < 512) {
    const int cgi = t >> 6, row = t & 63;       // W/K frags
    const int colg = cgi * 8;
    union { short8 v; unsigned short us[8]; } wb, kb;
#pragma unroll
    for (int jj = 0; jj < 8; ++jj) {
      wb.us[jj] = f2bfru(phi[row + 1 + colg + jj]);
      const int mm = colg + jj;
      kb.us[jj] = (mm <= row) ? f2bfru(kv[row - mm]) : (unsigned short)0;
    }
    *(short8*)(lds + FW_OFF + fmoff(row, colg)) = wb.v;
    *(short8*)(lds + FK_OFF + fmoff(row, colg)) = kb.v;
  }
  short8 At[4][2];
#pragma unroll
  for (int rt = 0; rt < 4; ++rt)
#pragma unroll
    for (int kt = 0; kt < 2; ++kt)
      At[rt][kt] = *(const short8*)(G + (64 + 16*rt + n16)*128 + 32*kt + quad*8);
  for (int idx = t; idx < 4096; idx += 1024) {  // T -> scrA f32 (disjoint of G)
    const int row = idx >> 6, col = idx & 63;
    scrA[row*64 + col] = bf2f(G[(64 + row)*128 + col]);
  }
  __syncthreads();

  // ---------------- T4 = (T^2)^2 via 2 squarings ----------------
  SQ_LEVEL(scrA, scrB);   // T2 (scrB aliases dead G region)
  __syncthreads();
  SQ_LEVEL(scrB, scrA);   // T4
  __syncthreads();
  if (w < 8) {            // At4 frags -> FT4
    const int rt4 = w >> 1, kt4 = w & 1;
    union { short8 v; unsigned short us[8]; } a4;
#pragma unroll
    for (int j = 0; j < 8; ++j)
      a4.us[j] = (short)f2bfru(scrA[(16*rt4 + n16)*64 + 32*kt4 + 8*quad + j]);
    *(short8*)(lds + FT4_OFF + (((rt4*2 + kt4)*64 + lane) << 4)) = a4.v;
  }
  __syncthreads();        // scratch + G dead -> slots usable

  // ---------------- pass1: 4 chunks/wave, local scan ----------------
  const float* upb = u   + (size_t)bqi * ((size_t)SL * DM) + 4*h;
  float*       opb = out + (size_t)bqi * ((size_t)SL * DM) + 4*h;
  const int c0 = 4 * w;                   // wave's first global chunk
  char* myslot = lds + SLOTS_OFF + c0 * 2048;
  const int srcA = n16 + 16*((2*quad) & 3);
  const int srcB = n16 + 16*((2*quad + 1) & 3);
  const bool hi = (quad >= 2);
  const short8 Z8 = {0,0,0,0,0,0,0,0};
  short8 B0 = Z8, B1 = Z8;

  PRODCHUNK(0);
  PRODCHUNK(1);
  PRODCHUNK(2);
  PRODCHUNK(3);
  __syncthreads();

  // ---------------- pass2: wave 0, 16 steps with T4 ----------------
  if (w == 0) {
    short8 At4[4][2];
#pragma unroll
    for (int rt = 0; rt < 4; ++rt)
#pragma unroll
      for (int kt = 0; kt < 2; ++kt)
        At4[rt][kt] = *(const short8*)(lds + FT4_OFF + (((rt*2 + kt)*64 + lane) << 4));
    B0 = Z8; B1 = Z8;
#pragma unroll 1
    for (int g = 0; g < 16; ++g) {
      char* sp = lds + SLOTS_OFF + (4*g + 3) * 2048;
      uint2 rb[4];
#pragma unroll
      for (int rt = 0; rt < 4; ++rt) rb[rt] = *(const uint2*)(sp + rt*512 + lane*8);
      asm volatile("" ::: "memory");
      *(short8*)(sp + lane*16)        = B0;   // entering state of group g
      *(short8*)(sp + 1024 + lane*16) = B1;
      unsigned pk[4][2];
#pragma unroll
      for (int rt = 0; rt < 4; ++rt) {
        floatx4 cs;
        cs[0] = bflo(rb[rt].x); cs[1] = bfhi(rb[rt].x);
        cs[2] = bflo(rb[rt].y); cs[3] = bfhi(rb[rt].y);
        floatx4 a0 = __builtin_amdgcn_mfma_f32_16x16x32_bf16(At4[rt][0], B0, cs, 0,0,0);
        floatx4 ac = __builtin_amdgcn_mfma_f32_16x16x32_bf16(At4[rt][1], B1, a0, 0,0,0);
        pk[rt][0] = pack_bf16(ac[0], ac[1]);
        pk[rt][1] = pack_bf16(ac[2], ac[3]);
      }
      CONV_PK(pk);
    }
  }
  __syncthreads();

  // ---------------- pass3: seed + 4 chunks/wave ----------------
  B0 = *(const short8*)(myslot + 3*2048 + lane*16);
  B1 = *(const short8*)(myslot + 3*2048 + 1024 + lane*16);
  CONSCHUNK(0);
  CONSCHUNK(1);
  CONSCHUNK(2);
  CONSCHUNK(3);
}

// ---------------------------------------------------------------- launch --
extern "C" void kernel_launch(void* const* d_in, const int* in_sizes, int n_in,
                              void* d_out, int out_size, void* d_ws, size_t ws_size,
                              hipStream_t stream)
{
  const float* u = (const float*)d_in[0];
  const float* a = (const float*)d_in[1];
  const float* b = (const float*)d_in[2];
  const float* c = (const float*)d_in[3];
  float* out = (float*)d_out;
  (void)d_ws; (void)ws_size; (void)in_sizes; (void)n_in; (void)out_size;

  fused_kernel<<<NKH, 1024, 0, stream>>>(u, a, b, c, out);
}

// Round 10
// 171.691 us; speedup vs baseline: 1.1959x; 1.1027x over previous
//
#include <hip/hip_runtime.h>

// CompanionSSM: 256 blocks (1 head each), 1024 threads = 16 waves.
// == Round-7 proven structure (77us steady, zero spills) + two latency fixes:
//  (1) producer loads split PLOAD/PCOMP: group g+2's float4 loads issue at
//      iteration g into persistent regs -> HBM latency off the critical path
//  (2) scanner SCANQ software-pipelined: next slot's R words preloaded
//      before the current step's shuffle-convert -> ds_read latency hidden
//  (3) __launch_bounds__(1024) (no occupancy hint): flat size already forces
//      the <=128 VGPR cap; avoids the 64-reg cap+spill seen in r8/r9
// Three-stage pipeline, tri-buffered (slot = group % 3), 1 barrier per group:
//   wave 0   : serial scan of group g      (R slot g%3 -> entering-S in place)
//   waves 1-8: produce group g+1           (PCOMP from prefetched regs ->
//              U-frags to LDS, R = V@U -> R slot (g+1)%3), PLOAD(g+2)
//   waves 8-15: consume group g-1          (Y = Toep@U + W@S from slot (g-1)%3,
//              qtr back -> float4 full-line stores)
// LDS: R 3x16KB + U 3x16KB + frags 24KB + phi/kv = 121KB (1 block/CU).

#define NKH 256
#define KD  64
#define SL  4096
#define DM  1024

typedef __attribute__((ext_vector_type(8))) short short8;
typedef __attribute__((ext_vector_type(4))) float floatx4;

#define RBUF_OFF  0
#define UBUF_OFF  49152
#define FV_OFF    98304
#define FW_OFF    106496
#define FK_OFF    114688
#define PHI_OFF   122880
#define KV_OFF    123392
#define LDS_TOTAL 123648

static __device__ __forceinline__ unsigned pack_bf16(float a, float b) {
  union { float f; unsigned u; } ua, ub;
  ua.f = a; ub.f = b;
  return __builtin_amdgcn_perm(ub.u + 0x8000u, ua.u + 0x8000u, 0x07060302u);
}
static __device__ __forceinline__ unsigned short f2bfru(float x) {
  union { float f; unsigned u; } v; v.f = x;
  return (unsigned short)((v.u + 0x8000u) >> 16);
}
static __device__ __forceinline__ float bflo(unsigned d) {
  union { unsigned u; float f; } v; v.u = d << 16; return v.f;
}
static __device__ __forceinline__ float bfhi(unsigned d) {
  union { unsigned u; float f; } v; v.u = d & 0xffff0000u; return v.f;
}
static __device__ __forceinline__ float bf2f(unsigned short s) {
  union { unsigned u; float f; } v; v.u = ((unsigned)s) << 16; return v.f;
}
static __device__ __forceinline__ float wredsum(float x) {
#pragma unroll
  for (int off = 32; off; off >>= 1) x += __shfl_xor(x, off, 64);
  return x;
}
// 4x4 transpose across a DPP quad (lanes 4k..4k+3, c = lane&3).
static __device__ __forceinline__ float4 qtr(float4 v, int c) {
  const bool c1 = (c & 1) != 0, c2 = (c & 2) != 0;
  float a01 = __shfl_xor(v.y, 1, 64), a10 = __shfl_xor(v.x, 1, 64);
  float a23 = __shfl_xor(v.w, 1, 64), a32 = __shfl_xor(v.z, 1, 64);
  float t0 = c1 ? a01 : v.x, t1 = c1 ? v.y : a10;
  float t2 = c1 ? a23 : v.z, t3 = c1 ? v.w : a32;
  float b02 = __shfl_xor(t2, 2, 64), b20 = __shfl_xor(t0, 2, 64);
  float b13 = __shfl_xor(t3, 2, 64), b31 = __shfl_xor(t1, 2, 64);
  float4 r;
  r.x = c2 ? b02 : t0; r.y = c2 ? b13 : t1;
  r.z = c2 ? t2 : b20; r.w = c2 ? t3 : b31;
  return r;
}
// frag-major 16B-group byte offset for 64x64 bf16
static __device__ __forceinline__ int fmoff(int row, int colg) {
  return ((((row >> 4) * 2 + (colg >> 5)) * 64 + ((colg >> 3) & 3) * 16 + (row & 15)) << 4);
}

// -------- producer load: group QN chunk pw -> persistent regs Lp0..Lp3 ----
#define PLOAD(QN) do { \
  const int qg_ = (QN) * 8 + pw; \
  Lp0 = *(const float4*)(upb + (size_t)(qg_*64 +      q8 +     rr) * DM); \
  Lp1 = *(const float4*)(upb + (size_t)(qg_*64 +      q8 + 4 + rr) * DM); \
  Lp2 = *(const float4*)(upb + (size_t)(qg_*64 + 32 + q8 +     rr) * DM); \
  Lp3 = *(const float4*)(upb + (size_t)(qg_*64 + 32 + q8 + 4 + rr) * DM); \
} while (0)

// -------- producer compute: prefetched regs -> U frags + R in slot SL3 ----
#define PCOMP(QN, SL3) do { \
  const float4 W00_ = qtr(Lp0, rr), W01_ = qtr(Lp1, rr); \
  const float4 W10_ = qtr(Lp2, rr), W11_ = qtr(Lp3, rr); \
  union { short8 v; unsigned s4[4]; } u0_, u1_; \
  u0_.s4[0] = pack_bf16(W00_.x, W00_.y); u0_.s4[1] = pack_bf16(W00_.z, W00_.w); \
  u0_.s4[2] = pack_bf16(W01_.x, W01_.y); u0_.s4[3] = pack_bf16(W01_.z, W01_.w); \
  u1_.s4[0] = pack_bf16(W10_.x, W10_.y); u1_.s4[1] = pack_bf16(W10_.z, W10_.w); \
  u1_.s4[2] = pack_bf16(W11_.x, W11_.y); u1_.s4[3] = pack_bf16(W11_.z, W11_.w); \
  char* us_ = lds + UBUF_OFF + (SL3) * 16384 + pw * 2048; \
  *(short8*)(us_ + lane*16)        = u0_.v; \
  *(short8*)(us_ + 1024 + lane*16) = u1_.v; \
  char* slot_ = lds + RBUF_OFF + (SL3) * 16384 + pw * 2048; \
  _Pragma("unroll") \
  for (int rt_ = 0; rt_ < 4; ++rt_) { \
    const short8 v0_ = *(const short8*)(lds + FV_OFF + (((rt_*2 + 0)*64 + lane) << 4)); \
    const short8 v1_ = *(const short8*)(lds + FV_OFF + (((rt_*2 + 1)*64 + lane) << 4)); \
    floatx4 r_ = {0.f, 0.f, 0.f, 0.f}; \
    r_ = __builtin_amdgcn_mfma_f32_16x16x32_bf16(v0_, u0_.v, r_, 0,0,0); \
    r_ = __builtin_amdgcn_mfma_f32_16x16x32_bf16(v1_, u1_.v, r_, 0,0,0); \
    uint2 pk_; pk_.x = pack_bf16(r_[0], r_[1]); pk_.y = pack_bf16(r_[2], r_[3]); \
    *(uint2*)(slot_ + rt_*512 + lane*8) = pk_; \
  } \
} while (0)

// -------- consumer wave (8..15): chunk cw of group QC from slot SL3 --------
#define CONSUME(QC, SL3) do { \
  const int qg_ = (QC) * 8 + cw; \
  char* ss_ = lds + RBUF_OFF + (SL3) * 16384 + cw * 2048; \
  const short8 S0_ = *(const short8*)(ss_ + lane*16); \
  const short8 S1_ = *(const short8*)(ss_ + 1024 + lane*16); \
  char* us_ = lds + UBUF_OFF + (SL3) * 16384 + cw * 2048; \
  const short8 U0_ = *(const short8*)(us_ + lane*16); \
  const short8 U1_ = *(const short8*)(us_ + 1024 + lane*16); \
  _Pragma("unroll") \
  for (int rt_ = 0; rt_ < 4; ++rt_) { \
    const short8 k0_ = *(const short8*)(lds + FK_OFF + (((rt_*2 + 0)*64 + lane) << 4)); \
    const short8 k1_ = *(const short8*)(lds + FK_OFF + (((rt_*2 + 1)*64 + lane) << 4)); \
    const short8 w0_ = *(const short8*)(lds + FW_OFF + (((rt_*2 + 0)*64 + lane) << 4)); \
    const short8 w1_ = *(const short8*)(lds + FW_OFF + (((rt_*2 + 1)*64 + lane) << 4)); \
    floatx4 ty_ = {0.f, 0.f, 0.f, 0.f}; \
    ty_ = __builtin_amdgcn_mfma_f32_16x16x32_bf16(k0_, U0_, ty_, 0,0,0); \
    ty_ = __builtin_amdgcn_mfma_f32_16x16x32_bf16(k1_, U1_, ty_, 0,0,0); \
    ty_ = __builtin_amdgcn_mfma_f32_16x16x32_bf16(w0_, S0_, ty_, 0,0,0); \
    ty_ = __builtin_amdgcn_mfma_f32_16x16x32_bf16(w1_, S1_, ty_, 0,0,0); \
    float4 yv_; yv_.x = ty_[0]; yv_.y = ty_[1]; yv_.z = ty_[2]; yv_.w = ty_[3]; \
    const float4 tw_ = qtr(yv_, rr); \
    *(float4*)(opb + (size_t)(qg_*64 + 16*rt_ + 4*quad + rr) * DM) = tw_; \
  } \
} while (0)

// -------- scanner (wave 0): group QN in slot SL3, R-read pipelined --------
#define SCANQ(QN, SL3) do { \
  char* rbuf_ = lds + RBUF_OFF + (SL3) * 16384; \
  uint2 rcur_[4]; \
  _Pragma("unroll") \
  for (int rt_ = 0; rt_ < 4; ++rt_) \
    rcur_[rt_] = *(const uint2*)(rbuf_ + rt_*512 + lane*8); \
  _Pragma("unroll") \
  for (int lq_ = 0; lq_ < 8; ++lq_) { \
    char* sp_ = rbuf_ + lq_ * 2048; \
    uint2 rnx_[4]; \
    if (lq_ < 7) { \
      _Pragma("unroll") \
      for (int rt_ = 0; rt_ < 4; ++rt_) \
        rnx_[rt_] = *(const uint2*)(sp_ + 2048 + rt_*512 + lane*8); \
    } \
    asm volatile("" ::: "memory"); \
    *(short8*)(sp_ + lane*16)        = B0; \
    *(short8*)(sp_ + 1024 + lane*16) = B1; \
    unsigned pk_[4][2]; \
    _Pragma("unroll") \
    for (int rt_ = 0; rt_ < 4; ++rt_) { \
      floatx4 cs_; \
      cs_[0] = bflo(rcur_[rt_].x); cs_[1] = bfhi(rcur_[rt_].x); \
      cs_[2] = bflo(rcur_[rt_].y); cs_[3] = bfhi(rcur_[rt_].y); \
      floatx4 a0_ = __builtin_amdgcn_mfma_f32_16x16x32_bf16(At[rt_][0], B0, cs_, 0,0,0); \
      floatx4 ac_ = __builtin_amdgcn_mfma_f32_16x16x32_bf16(At[rt_][1], B1, a0_, 0,0,0); \
      pk_[rt_][0] = pack_bf16(ac_[0], ac_[1]); \
      pk_[rt_][1] = pack_bf16(ac_[2], ac_[3]); \
    } \
    union { short8 v; unsigned uu[4]; } nb0_, nb1_; \
    unsigned xa_, xb_; \
    xa_ = __shfl(pk_[0][0], srcA, 64); xb_ = __shfl(pk_[1][0], srcA, 64); nb0_.uu[0] = hi ? xb_ : xa_; \
    xa_ = __shfl(pk_[0][1], srcA, 64); xb_ = __shfl(pk_[1][1], srcA, 64); nb0_.uu[1] = hi ? xb_ : xa_; \
    xa_ = __shfl(pk_[0][0], srcB, 64); xb_ = __shfl(pk_[1][0], srcB, 64); nb0_.uu[2] = hi ? xb_ : xa_; \
    xa_ = __shfl(pk_[0][1], srcB, 64); xb_ = __shfl(pk_[1][1], srcB, 64); nb0_.uu[3] = hi ? xb_ : xa_; \
    xa_ = __shfl(pk_[2][0], srcA, 64); xb_ = __shfl(pk_[3][0], srcA, 64); nb1_.uu[0] = hi ? xb_ : xa_; \
    xa_ = __shfl(pk_[2][1], srcA, 64); xb_ = __shfl(pk_[3][1], srcA, 64); nb1_.uu[1] = hi ? xb_ : xa_; \
    xa_ = __shfl(pk_[2][0], srcB, 64); xb_ = __shfl(pk_[3][0], srcB, 64); nb1_.uu[2] = hi ? xb_ : xa_; \
    xa_ = __shfl(pk_[2][1], srcB, 64); xb_ = __shfl(pk_[3][1], srcB, 64); nb1_.uu[3] = hi ? xb_ : xa_; \
    B0 = nb0_.v; B1 = nb1_.v; \
    if (lq_ < 7) { \
      _Pragma("unroll") \
      for (int rt_ = 0; rt_ < 4; ++rt_) rcur_[rt_] = rnx_[rt_]; \
    } \
  } \
} while (0)

__global__ __launch_bounds__(1024) void fused_kernel(
    const float* __restrict__ u, const float* __restrict__ ga,
    const float* __restrict__ gb, const float* __restrict__ gc,
    float* __restrict__ out)
{
  __shared__ __align__(16) char lds[LDS_TOTAL];
  unsigned short* G = (unsigned short*)lds;     // prep: rows 64..127, stride 128
  float* phi = (float*)(lds + PHI_OFF);
  float* kv  = (float*)(lds + KV_OFF);

  const int i = blockIdx.x;
  const int h = 8 * (i & 31) + (i >> 5);        // co-line heads -> same XCD
  const int t = threadIdx.x;
  const int w = t >> 6, lane = t & 63;
  const int n16 = lane & 15, quad = lane >> 4;
  const int rr = lane & 3, q8 = quad * 8, bqi = (lane >> 2) & 3;
  const int pw = w - 1;                         // producer chunk (waves 1..8)
  const int cw = w - 8;                         // consumer chunk (waves 8..15)

  // ---------------- prep chains (waves 0,1; no in-loop reductions) --------
  if (w < 2) {
    const float av = ga[h*KD + lane];
    const float an = av / wredsum(fabsf(av));   // mean(|rowsum|) >> eps
    if (w == 1) {
      phi[lane] = gc[h*KD + lane];              // phi[0..63] = c
      float g = an;                             // g_64 = A^64 e0 = a_n
      for (int p = 64; p < 128; ++p) {
        G[(64 + lane)*128 + (p - 64)] = f2bfru(g);   // T col m = g_{64+m}
        const float top = __shfl(g, 63, 64);
        const float gm1 = __shfl_up(g, 1, 64);
        g = (lane > 0 ? gm1 : 0.0f) + an * top;
      }
    } else {
      float v = gb[h*KD + lane];                // v_j = A^j b
      for (int j = 0; j < KD; ++j) {
        G[(64 + lane)*128 + 64 + (63 - j)] = f2bfru(v);  // V col m = v_{63-m}
        const float top = __shfl(v, 63, 64);
        const float vm1 = __shfl_up(v, 1, 64);
        v = (lane > 0 ? vm1 : 0.0f) + an * top;
      }
    }
  }
  __syncthreads();

  // ------- deferred dot products: phi[64..127] and kv[0..63] -------
  if (t < 128) {
    float acc = 0.f;
    for (int n = 0; n < 64; ++n)
      acc += phi[n] * bf2f(G[(64 + n)*128 + t]);
    if (t < 64) phi[64 + t] = acc;      // phi[p] = c . g_p
    else        kv[127 - t] = acc;      // kv[j] = c . v_j
  }
  __syncthreads();

  // ---------------- frag-major fills: V copy, W/K direct; wave0 At --------
  if (t < 512) {
    const int f = t >> 6, l = t & 63;           // V: one 16B group per thread
    const int rt = f >> 1, kt = f & 1;
    const int ln = l & 15, lq2 = l >> 4;
    *(uint4*)(lds + FV_OFF + ((f*64 + l) << 4)) =
        *(const uint4*)(G + (64 + 16*rt + ln)*128 + 64 + 32*kt + 8*lq2);
  }
  if (t < 512) {
    const int cgi = t >> 6, row = t & 63;       // W/K: 64 rows x 8 colgroups
    const int colg = cgi * 8;
    union { short8 v; unsigned short us[8]; } wb, kb;
#pragma unroll
    for (int jj = 0; jj < 8; ++jj) {
      wb.us[jj] = f2bfru(phi[row + 1 + colg + jj]);
      const int mm = colg + jj;
      kb.us[jj] = (mm <= row) ? f2bfru(kv[row - mm]) : (unsigned short)0;
    }
    *(short8*)(lds + FW_OFF + fmoff(row, colg)) = wb.v;
    *(short8*)(lds + FK_OFF + fmoff(row, colg)) = kb.v;
  }
  short8 At[4][2];
  if (w == 0) {
#pragma unroll
    for (int rt = 0; rt < 4; ++rt)
#pragma unroll
      for (int kt = 0; kt < 2; ++kt)
        At[rt][kt] = *(const short8*)(G + (64 + 16*rt + n16)*128 + 32*kt + quad*8);
  }
  __syncthreads();   // G (aliasing Rbuf slots 0/1) dead -> buffers usable

  // ---------------- main: 8 groups x 8 chunks, 3-stage pipeline ----------
  const float* upb = u   + (size_t)bqi * ((size_t)SL * DM) + 4*h;
  float*       opb = out + (size_t)bqi * ((size_t)SL * DM) + 4*h;
  const int srcA = n16 + 16*((2*quad) & 3);
  const int srcB = n16 + 16*((2*quad + 1) & 3);
  const bool hi = (quad >= 2);
  const short8 Z8 = {0,0,0,0,0,0,0,0};
  short8 B0 = Z8, B1 = Z8;                // scan carry (wave 0)
  float4 Lp0, Lp1, Lp2, Lp3;              // producer prefetch regs
  const bool isP = (w >= 1 && w <= 8);
  const bool isC = (w >= 8);

  if (isP) { PLOAD(0); PCOMP(0, 0); PLOAD(1); }
  __syncthreads();

  // iter 0: scan(0,s0) || pcomp(1,s1)+pload(2)
  if (w == 0) SCANQ(0, 0);
  if (isP) { PCOMP(1, 1); PLOAD(2); }
  __syncthreads();
  // iters 1..6: scan(g) || pcomp(g+1)+pload(g+2) || consume(g-1)  (mod 3)
  if (w == 0) SCANQ(1, 1);
  if (isP) { PCOMP(2, 2); PLOAD(3); }
  if (isC) CONSUME(0, 0);
  __syncthreads();
  if (w == 0) SCANQ(2, 2);
  if (isP) { PCOMP(3, 0); PLOAD(4); }
  if (isC) CONSUME(1, 1);
  __syncthreads();
  if (w == 0) SCANQ(3, 0);
  if (isP) { PCOMP(4, 1); PLOAD(5); }
  if (isC) CONSUME(2, 2);
  __syncthreads();
  if (w == 0) SCANQ(4, 1);
  if (isP) { PCOMP(5, 2); PLOAD(6); }
  if (isC) CONSUME(3, 0);
  __syncthreads();
  if (w == 0) SCANQ(5, 2);
  if (isP) { PCOMP(6, 0); PLOAD(7); }
  if (isC) CONSUME(4, 1);
  __syncthreads();
  if (w == 0) SCANQ(6, 0);
  if (isP) PCOMP(7, 1);
  if (isC) CONSUME(5, 2);
  __syncthreads();
  // iter 7: scan(7,s1) || consume(6,s0)
  if (w == 0) SCANQ(7, 1);
  if (isC) CONSUME(6, 0);
  __syncthreads();
  // tail: consume(7,s1)
  if (isC) CONSUME(7, 1);
}

// ---------------------------------------------------------------- launch --
extern "C" void kernel_launch(void* const* d_in, const int* in_sizes, int n_in,
                              void* d_out, int out_size, void* d_ws, size_t ws_size,
                              hipStream_t stream)
{
  const float* u = (const float*)d_in[0];
  const float* a = (const float*)d_in[1];
  const float* b = (const float*)d_in[2];
  const float* c = (const float*)d_in[3];
  float* out = (float*)d_out;
  (void)d_ws; (void)ws_size; (void)in_sizes; (void)n_in; (void)out_size;

  fused_kernel<<<NKH, 1024, 0, stream>>>(u, a, b, c, out);
}

// Round 11
// 161.373 us; speedup vs baseline: 1.2724x; 1.0639x over previous
//
#include <hip/hip_runtime.h>

// CompanionSSM: 256 blocks (1 head), 512 thr = 8 waves, Blelloch scan at a
// register budget that fits (2 waves/SIMD -> 256 VGPR cap; r8/r9's spills
// came from the 64-reg cap at 1024 thr).  UB kept in registers (no re-read).
//  pass1: wave w, chunks 8w..8w+7: load (float4+qtr), UB[j] regs, R=V@U;
//         j<7: R pk -> slot 8w+j, local step B<-T@B+R (f32 C-input);
//         j==7: stepped B (group Rsum) pk -> slot 8w+7.
//  pass2: wave 0: 8 steps with T8 frags (3 hi/lo-split MFMA squarings,
//         r1-verified); entering group states written in place over Rsums.
//  pass3: wave w: seed from slot 8w+7; per chunk Y = Toep@UB[j] + W@S
//         (qtr back, full-line float4 stores); j<7: step via stored R pk.
// Serial critical path: 64 steps (r0/r7) -> 8+8+7.  2 main barriers.
// LDS 160KB exact: 64 slots 128KB (alias prep G + SQ scratch + phi/kv) +
// FV/FW/FK/FT8 frags 32KB.

#define NKH 256
#define KD  64
#define SL  4096
#define DM  1024

typedef __attribute__((ext_vector_type(8))) short short8;
typedef __attribute__((ext_vector_type(4))) float floatx4;

#define SLOTS_OFF 0
#define SCRA_OFF  0          // f32 64x64  [0,16384)      (slots 0..7)
#define SCRB_OFF  16384      // f32 64x64  [16384,32768)  (= prep G region)
#define PHI_OFF   32768      // f32[128]   (slot-16 region, prep-only)
#define KV_OFF    33280      // f32[64]
#define FV_OFF    131072
#define FW_OFF    139264
#define FK_OFF    147456
#define FT8_OFF   155648
#define LDS_TOTAL 163840

static __device__ __forceinline__ unsigned pack_bf16(float a, float b) {
  union { float f; unsigned u; } ua, ub;
  ua.f = a; ub.f = b;
  return __builtin_amdgcn_perm(ub.u + 0x8000u, ua.u + 0x8000u, 0x07060302u);
}
static __device__ __forceinline__ unsigned short f2bfru(float x) {
  union { float f; unsigned u; } v; v.f = x;
  return (unsigned short)((v.u + 0x8000u) >> 16);
}
static __device__ __forceinline__ float bflo(unsigned d) {
  union { unsigned u; float f; } v; v.u = d << 16; return v.f;
}
static __device__ __forceinline__ float bfhi(unsigned d) {
  union { unsigned u; float f; } v; v.u = d & 0xffff0000u; return v.f;
}
static __device__ __forceinline__ float bf2f(unsigned short s) {
  union { unsigned u; float f; } v; v.u = ((unsigned)s) << 16; return v.f;
}
static __device__ __forceinline__ float wredsum(float x) {
#pragma unroll
  for (int off = 32; off; off >>= 1) x += __shfl_xor(x, off, 64);
  return x;
}
// 4x4 transpose across a DPP quad (lanes 4k..4k+3, c = lane&3).
static __device__ __forceinline__ float4 qtr(float4 v, int c) {
  const bool c1 = (c & 1) != 0, c2 = (c & 2) != 0;
  float a01 = __shfl_xor(v.y, 1, 64), a10 = __shfl_xor(v.x, 1, 64);
  float a23 = __shfl_xor(v.w, 1, 64), a32 = __shfl_xor(v.z, 1, 64);
  float t0 = c1 ? a01 : v.x, t1 = c1 ? v.y : a10;
  float t2 = c1 ? a23 : v.z, t3 = c1 ? v.w : a32;
  float b02 = __shfl_xor(t2, 2, 64), b20 = __shfl_xor(t0, 2, 64);
  float b13 = __shfl_xor(t3, 2, 64), b31 = __shfl_xor(t1, 2, 64);
  float4 r;
  r.x = c2 ? b02 : t0; r.y = c2 ? b13 : t1;
  r.z = c2 ? t2 : b20; r.w = c2 ? t3 : b31;
  return r;
}
// frag-major 16B-group byte offset for 64x64 bf16
static __device__ __forceinline__ int fmoff(int row, int colg) {
  return ((((row >> 4) * 2 + (colg >> 5)) * 64 + ((colg >> 3) & 3) * 16 + (row & 15)) << 4);
}

// pk (C-layout packed) -> B-frag conversion via 16 shfl (r0-r10 verified)
#define CONV_PK(PK) do { \
  union { short8 v; unsigned uu[4]; } nb0_, nb1_; \
  unsigned xa_, xb_; \
  xa_ = __shfl(PK[0][0], srcA, 64); xb_ = __shfl(PK[1][0], srcA, 64); nb0_.uu[0] = hi ? xb_ : xa_; \
  xa_ = __shfl(PK[0][1], srcA, 64); xb_ = __shfl(PK[1][1], srcA, 64); nb0_.uu[1] = hi ? xb_ : xa_; \
  xa_ = __shfl(PK[0][0], srcB, 64); xb_ = __shfl(PK[1][0], srcB, 64); nb0_.uu[2] = hi ? xb_ : xa_; \
  xa_ = __shfl(PK[0][1], srcB, 64); xb_ = __shfl(PK[1][1], srcB, 64); nb0_.uu[3] = hi ? xb_ : xa_; \
  xa_ = __shfl(PK[2][0], srcA, 64); xb_ = __shfl(PK[3][0], srcA, 64); nb1_.uu[0] = hi ? xb_ : xa_; \
  xa_ = __shfl(PK[2][1], srcA, 64); xb_ = __shfl(PK[3][1], srcA, 64); nb1_.uu[1] = hi ? xb_ : xa_; \
  xa_ = __shfl(PK[2][0], srcB, 64); xb_ = __shfl(PK[3][0], srcB, 64); nb1_.uu[2] = hi ? xb_ : xa_; \
  xa_ = __shfl(PK[2][1], srcB, 64); xb_ = __shfl(PK[3][1], srcB, 64); nb1_.uu[3] = hi ? xb_ : xa_; \
  B0 = nb0_.v; B1 = nb1_.v; \
} while (0)

// one squaring level: DST = SRC @ SRC (64x64 f32, stride 64), hi/lo bf16
// split; 16 tiles = 2 per wave (8 waves).  r1-verified math.
#define SQ_LEVEL(SRC, DST) do { \
  _Pragma("unroll") \
  for (int tt_ = 0; tt_ < 2; ++tt_) { \
    const int rt_ = (2*w + tt_) >> 2, ct_ = (2*w + tt_) & 3; \
    short8 Ah_[2], Al_[2], Bh_[2], Bl_[2]; \
    _Pragma("unroll") \
    for (int kt_ = 0; kt_ < 2; ++kt_) { \
      const float* ap_ = (SRC) + (16*rt_ + n16)*64 + 32*kt_ + 8*quad; \
      union { short8 v; unsigned short us[8]; } ah_, al_, bh_, bl_; \
      _Pragma("unroll") \
      for (int j_ = 0; j_ < 8; ++j_) { \
        float x_ = ap_[j_]; \
        unsigned short hu_ = f2bfru(x_); \
        ah_.us[j_] = (short)hu_; al_.us[j_] = (short)f2bfru(x_ - bf2f(hu_)); \
      } \
      _Pragma("unroll") \
      for (int j_ = 0; j_ < 8; ++j_) { \
        float x_ = (SRC)[(32*kt_ + 8*quad + j_)*64 + 16*ct_ + n16]; \
        unsigned short hu_ = f2bfru(x_); \
        bh_.us[j_] = (short)hu_; bl_.us[j_] = (short)f2bfru(x_ - bf2f(hu_)); \
      } \
      Ah_[kt_] = ah_.v; Al_[kt_] = al_.v; Bh_[kt_] = bh_.v; Bl_[kt_] = bl_.v; \
    } \
    floatx4 d_ = {0.f, 0.f, 0.f, 0.f}; \
    _Pragma("unroll") \
    for (int kt_ = 0; kt_ < 2; ++kt_) { \
      d_ = __builtin_amdgcn_mfma_f32_16x16x32_bf16(Ah_[kt_], Bh_[kt_], d_, 0,0,0); \
      d_ = __builtin_amdgcn_mfma_f32_16x16x32_bf16(Ah_[kt_], Bl_[kt_], d_, 0,0,0); \
      d_ = __builtin_amdgcn_mfma_f32_16x16x32_bf16(Al_[kt_], Bh_[kt_], d_, 0,0,0); \
    } \
    _Pragma("unroll") \
    for (int r_ = 0; r_ < 4; ++r_) \
      (DST)[(16*rt_ + 4*quad + r_)*64 + 16*ct_ + n16] = d_[r_]; \
  } \
} while (0)

// load chunk at row base ROW0: 4 float4/lane, full-line (r7-r10 verified)
#define LOADC(ROW0, L) do { \
  L[0] = *(const float4*)(upb + (size_t)((ROW0) + q8 +     rr) * DM); \
  L[1] = *(const float4*)(upb + (size_t)((ROW0) + q8 + 4 + rr) * DM); \
  L[2] = *(const float4*)(upb + (size_t)((ROW0) + 32 + q8 +     rr) * DM); \
  L[3] = *(const float4*)(upb + (size_t)((ROW0) + 32 + q8 + 4 + rr) * DM); \
} while (0)

// pass1 chunk J from loaded regs L: UB[J] <- transpose/pack; R = V@U;
// J<7: R pk -> slot J, step B <- T@B + R (f32 C-input);
// J==7: stepped B (group Rsum) pk -> slot 7.
#define PRODCHUNK(J, L) do { \
  const float4 W00_ = qtr(L[0], rr), W01_ = qtr(L[1], rr); \
  const float4 W10_ = qtr(L[2], rr), W11_ = qtr(L[3], rr); \
  union { short8 v; unsigned s4[4]; } u0_, u1_; \
  u0_.s4[0] = pack_bf16(W00_.x, W00_.y); u0_.s4[1] = pack_bf16(W00_.z, W00_.w); \
  u0_.s4[2] = pack_bf16(W01_.x, W01_.y); u0_.s4[3] = pack_bf16(W01_.z, W01_.w); \
  u1_.s4[0] = pack_bf16(W10_.x, W10_.y); u1_.s4[1] = pack_bf16(W10_.z, W10_.w); \
  u1_.s4[2] = pack_bf16(W11_.x, W11_.y); u1_.s4[3] = pack_bf16(W11_.z, W11_.w); \
  UB[J][0] = u0_.v; UB[J][1] = u1_.v; \
  floatx4 racc_[4]; \
  _Pragma("unroll") \
  for (int rt_ = 0; rt_ < 4; ++rt_) { \
    const short8 v0_ = *(const short8*)(lds + FV_OFF + (((rt_*2 + 0)*64 + lane) << 4)); \
    const short8 v1_ = *(const short8*)(lds + FV_OFF + (((rt_*2 + 1)*64 + lane) << 4)); \
    floatx4 r_ = {0.f, 0.f, 0.f, 0.f}; \
    r_ = __builtin_amdgcn_mfma_f32_16x16x32_bf16(v0_, u0_.v, r_, 0,0,0); \
    racc_[rt_] = __builtin_amdgcn_mfma_f32_16x16x32_bf16(v1_, u1_.v, r_, 0,0,0); \
  } \
  if ((J) < 7) { \
    _Pragma("unroll") \
    for (int rt_ = 0; rt_ < 4; ++rt_) { \
      uint2 pr_; pr_.x = pack_bf16(racc_[rt_][0], racc_[rt_][1]); \
      pr_.y = pack_bf16(racc_[rt_][2], racc_[rt_][3]); \
      *(uint2*)(myslot + (J)*2048 + rt_*512 + lane*8) = pr_; \
    } \
  } \
  unsigned pk_[4][2]; \
  _Pragma("unroll") \
  for (int rt_ = 0; rt_ < 4; ++rt_) { \
    floatx4 a0_ = __builtin_amdgcn_mfma_f32_16x16x32_bf16(At[rt_][0], B0, racc_[rt_], 0,0,0); \
    floatx4 ac_ = __builtin_amdgcn_mfma_f32_16x16x32_bf16(At[rt_][1], B1, a0_, 0,0,0); \
    pk_[rt_][0] = pack_bf16(ac_[0], ac_[1]); \
    pk_[rt_][1] = pack_bf16(ac_[2], ac_[3]); \
  } \
  if ((J) < 7) { CONV_PK(pk_); } \
  else { \
    _Pragma("unroll") \
    for (int rt_ = 0; rt_ < 4; ++rt_) { \
      uint2 pq_; pq_.x = pk_[rt_][0]; pq_.y = pk_[rt_][1]; \
      *(uint2*)(myslot + 7*2048 + rt_*512 + lane*8) = pq_; \
    } \
  } \
} while (0)

// pass3 chunk J: Y = Toep@UB[J] + W@B (store); J<7: step B via slot-J R pk.
#define CONSCHUNK(J) do { \
  _Pragma("unroll") \
  for (int rt_ = 0; rt_ < 4; ++rt_) { \
    const short8 k0_ = *(const short8*)(lds + FK_OFF + (((rt_*2 + 0)*64 + lane) << 4)); \
    const short8 k1_ = *(const short8*)(lds + FK_OFF + (((rt_*2 + 1)*64 + lane) << 4)); \
    const short8 w0_ = *(const short8*)(lds + FW_OFF + (((rt_*2 + 0)*64 + lane) << 4)); \
    const short8 w1_ = *(const short8*)(lds + FW_OFF + (((rt_*2 + 1)*64 + lane) << 4)); \
    floatx4 ty_ = {0.f, 0.f, 0.f, 0.f}; \
    ty_ = __builtin_amdgcn_mfma_f32_16x16x32_bf16(k0_, UB[J][0], ty_, 0,0,0); \
    ty_ = __builtin_amdgcn_mfma_f32_16x16x32_bf16(k1_, UB[J][1], ty_, 0,0,0); \
    ty_ = __builtin_amdgcn_mfma_f32_16x16x32_bf16(w0_, B0, ty_, 0,0,0); \
    ty_ = __builtin_amdgcn_mfma_f32_16x16x32_bf16(w1_, B1, ty_, 0,0,0); \
    float4 yv_; yv_.x = ty_[0]; yv_.y = ty_[1]; yv_.z = ty_[2]; yv_.w = ty_[3]; \
    const float4 tw_ = qtr(yv_, rr); \
    *(float4*)(opb + (size_t)((c0 + (J))*64 + 16*rt_ + 4*quad + rr) * DM) = tw_; \
  } \
  if ((J) < 7) { \
    uint2 rb_[4]; \
    _Pragma("unroll") \
    for (int rt_ = 0; rt_ < 4; ++rt_) \
      rb_[rt_] = *(const uint2*)(myslot + (J)*2048 + rt_*512 + lane*8); \
    unsigned pk_[4][2]; \
    _Pragma("unroll") \
    for (int rt_ = 0; rt_ < 4; ++rt_) { \
      floatx4 cs_; \
      cs_[0] = bflo(rb_[rt_].x); cs_[1] = bfhi(rb_[rt_].x); \
      cs_[2] = bflo(rb_[rt_].y); cs_[3] = bfhi(rb_[rt_].y); \
      floatx4 a0_ = __builtin_amdgcn_mfma_f32_16x16x32_bf16(At[rt_][0], B0, cs_, 0,0,0); \
      floatx4 ac_ = __builtin_amdgcn_mfma_f32_16x16x32_bf16(At[rt_][1], B1, a0_, 0,0,0); \
      pk_[rt_][0] = pack_bf16(ac_[0], ac_[1]); \
      pk_[rt_][1] = pack_bf16(ac_[2], ac_[3]); \
    } \
    CONV_PK(pk_); \
  } \
} while (0)

__global__ __launch_bounds__(512, 2) void fused_kernel(
    const float* __restrict__ u, const float* __restrict__ ga,
    const float* __restrict__ gb, const float* __restrict__ gc,
    float* __restrict__ out)
{
  __shared__ __align__(16) char lds[LDS_TOTAL];
  unsigned short* G = (unsigned short*)lds;     // prep: rows 64..127, stride 128
  float* phi  = (float*)(lds + PHI_OFF);
  float* kv   = (float*)(lds + KV_OFF);
  float* scrA = (float*)(lds + SCRA_OFF);
  float* scrB = (float*)(lds + SCRB_OFF);

  const int i = blockIdx.x;
  const int h = 8 * (i & 31) + (i >> 5);        // co-line heads -> same XCD
  const int t = threadIdx.x;
  const int w = t >> 6, lane = t & 63;
  const int n16 = lane & 15, quad = lane >> 4;
  const int rr = lane & 3, q8 = quad * 8, bqi = (lane >> 2) & 3;

  // ---------------- prep chains (waves 0,1; no in-loop reductions) --------
  if (w < 2) {
    const float av = ga[h*KD + lane];
    const float an = av / wredsum(fabsf(av));   // mean(|rowsum|) >> eps
    if (w == 1) {
      phi[lane] = gc[h*KD + lane];              // phi[0..63] = c
      float g = an;                             // g_64 = A^64 e0 = a_n
      for (int p = 64; p < 128; ++p) {
        G[(64 + lane)*128 + (p - 64)] = f2bfru(g);   // T col m = g_{64+m}
        const float top = __shfl(g, 63, 64);
        const float gm1 = __shfl_up(g, 1, 64);
        g = (lane > 0 ? gm1 : 0.0f) + an * top;
      }
    } else {
      float v = gb[h*KD + lane];                // v_j = A^j b
      for (int j = 0; j < KD; ++j) {
        G[(64 + lane)*128 + 64 + (63 - j)] = f2bfru(v);  // V col m = v_{63-m}
        const float top = __shfl(v, 63, 64);
        const float vm1 = __shfl_up(v, 1, 64);
        v = (lane > 0 ? vm1 : 0.0f) + an * top;
      }
    }
  }
  __syncthreads();

  // ------- deferred dot products: phi[64..127] and kv[0..63] -------
  if (t < 128) {
    float acc = 0.f;
    for (int n = 0; n < 64; ++n)
      acc += phi[n] * bf2f(G[(64 + n)*128 + t]);
    if (t < 64) phi[64 + t] = acc;      // phi[p] = c . g_p
    else        kv[127 - t] = acc;      // kv[j] = c . v_j
  }
  __syncthreads();

  // ---- fills: FV copy, FW/FK direct, At (all waves), T -> scrA (f32) ----
  {
    const int f = t >> 6, l = t & 63;           // V frags: 8 x 64 groups
    const int rt = f >> 1, kt = f & 1;
    const int ln = l & 15, lq2 = l >> 4;
    *(uint4*)(lds + FV_OFF + ((f*64 + l) << 4)) =
        *(const uint4*)(G + (64 + 16*rt + ln)*128 + 64 + 32*kt + 8*lq2);
  }
  {
    const int cgi = t >> 6, row = t & 63;       // W/K frags: 64 rows x 8 cg
    const int colg = cgi * 8;
    union { short8 v; unsigned short us[8]; } wb, kb;
#pragma unroll
    for (int jj = 0; jj < 8; ++jj) {
      wb.us[jj] = f2bfru(phi[row + 1 + colg + jj]);
      const int mm = colg + jj;
      kb.us[jj] = (mm <= row) ? f2bfru(kv[row - mm]) : (unsigned short)0;
    }
    *(short8*)(lds + FW_OFF + fmoff(row, colg)) = wb.v;
    *(short8*)(lds + FK_OFF + fmoff(row, colg)) = kb.v;
  }
  short8 At[4][2];
#pragma unroll
  for (int rt = 0; rt < 4; ++rt)
#pragma unroll
    for (int kt = 0; kt < 2; ++kt)
      At[rt][kt] = *(const short8*)(G + (64 + 16*rt + n16)*128 + 32*kt + quad*8);
  for (int idx = t; idx < 4096; idx += 512) {   // T -> scrA f32 (disjoint of G)
    const int row = idx >> 6, col = idx & 63;
    scrA[row*64 + col] = bf2f(G[(64 + row)*128 + col]);
  }
  __syncthreads();

  // ---------------- T8 = ((T^2)^2)^2 via 3 squarings ----------------
  SQ_LEVEL(scrA, scrB);   // T2 (scrB aliases dead G region)
  __syncthreads();
  SQ_LEVEL(scrB, scrA);   // T4
  __syncthreads();
  SQ_LEVEL(scrA, scrB);   // T8
  __syncthreads();
  {                       // At8 frags -> FT8 (one frag per wave)
    const int rt8 = w >> 1, kt8 = w & 1;
    union { short8 v; unsigned short us[8]; } a8;
#pragma unroll
    for (int j = 0; j < 8; ++j)
      a8.us[j] = (short)f2bfru(scrB[(16*rt8 + n16)*64 + 32*kt8 + 8*quad + j]);
    *(short8*)(lds + FT8_OFF + (((rt8*2 + kt8)*64 + lane) << 4)) = a8.v;
  }
  __syncthreads();        // scratch + G dead -> slots usable

  // ---------------- pass1: 8 chunks/wave, local scan, UB in regs ----------
  const float* upb = u   + (size_t)bqi * ((size_t)SL * DM) + 4*h;
  float*       opb = out + (size_t)bqi * ((size_t)SL * DM) + 4*h;
  const int c0 = 8 * w;                   // wave's first global chunk
  char* myslot = lds + SLOTS_OFF + c0 * 2048;
  const int srcA = n16 + 16*((2*quad) & 3);
  const int srcB = n16 + 16*((2*quad + 1) & 3);
  const bool hi = (quad >= 2);
  const short8 Z8 = {0,0,0,0,0,0,0,0};
  short8 B0 = Z8, B1 = Z8;
  short8 UB[8][2];

  {
    float4 LA[4], LB[4];
    LOADC(c0*64, LA);
    LOADC((c0 + 1)*64, LB);
    PRODCHUNK(0, LA); LOADC((c0 + 2)*64, LA);
    PRODCHUNK(1, LB); LOADC((c0 + 3)*64, LB);
    PRODCHUNK(2, LA); LOADC((c0 + 4)*64, LA);
    PRODCHUNK(3, LB); LOADC((c0 + 5)*64, LB);
    PRODCHUNK(4, LA); LOADC((c0 + 6)*64, LA);
    PRODCHUNK(5, LB); LOADC((c0 + 7)*64, LB);
    PRODCHUNK(6, LA);
    PRODCHUNK(7, LB);
  }
  __syncthreads();

  // ---------------- pass2: wave 0, 8 steps with T8 ----------------
  if (w == 0) {
    short8 At8[4][2];
#pragma unroll
    for (int rt = 0; rt < 4; ++rt)
#pragma unroll
      for (int kt = 0; kt < 2; ++kt)
        At8[rt][kt] = *(const short8*)(lds + FT8_OFF + (((rt*2 + kt)*64 + lane) << 4));
    B0 = Z8; B1 = Z8;
#pragma unroll 1
    for (int g = 0; g < 8; ++g) {
      char* sp = lds + SLOTS_OFF + (8*g + 7) * 2048;
      uint2 rb[4];
#pragma unroll
      for (int rt = 0; rt < 4; ++rt) rb[rt] = *(const uint2*)(sp + rt*512 + lane*8);
      asm volatile("" ::: "memory");
      *(short8*)(sp + lane*16)        = B0;   // entering state of group g
      *(short8*)(sp + 1024 + lane*16) = B1;
      unsigned pk[4][2];
#pragma unroll
      for (int rt = 0; rt < 4; ++rt) {
        floatx4 cs;
        cs[0] = bflo(rb[rt].x); cs[1] = bfhi(rb[rt].x);
        cs[2] = bflo(rb[rt].y); cs[3] = bfhi(rb[rt].y);
        floatx4 a0 = __builtin_amdgcn_mfma_f32_16x16x32_bf16(At8[rt][0], B0, cs, 0,0,0);
        floatx4 ac = __builtin_amdgcn_mfma_f32_16x16x32_bf16(At8[rt][1], B1, a0, 0,0,0);
        pk[rt][0] = pack_bf16(ac[0], ac[1]);
        pk[rt][1] = pack_bf16(ac[2], ac[3]);
      }
      CONV_PK(pk);
    }
  }
  __syncthreads();

  // ---------------- pass3: seed + 8 chunks/wave ----------------
  B0 = *(const short8*)(myslot + 7*2048 + lane*16);
  B1 = *(const short8*)(myslot + 7*2048 + 1024 + lane*16);
  CONSCHUNK(0);
  CONSCHUNK(1);
  CONSCHUNK(2);
  CONSCHUNK(3);
  CONSCHUNK(4);
  CONSCHUNK(5);
  CONSCHUNK(6);
  CONSCHUNK(7);
}

// ---------------------------------------------------------------- launch --
extern "C" void kernel_launch(void* const* d_in, const int* in_sizes, int n_in,
                              void* d_out, int out_size, void* d_ws, size_t ws_size,
                              hipStream_t stream)
{
  const float* u = (const float*)d_in[0];
  const float* a = (const float*)d_in[1];
  const float* b = (const float*)d_in[2];
  const float* c = (const float*)d_in[3];
  float* out = (float*)d_out;
  (void)d_ws; (void)ws_size; (void)in_sizes; (void)n_in; (void)out_size;

  fused_kernel<<<NKH, 512, 0, stream>>>(u, a, b, c, out);
}